// Round 2
// baseline (5062.669 us; speedup 1.0000x reference)
//
#include <hip/hip_runtime.h>
#include <hip/hip_fp8.h>
#include <math.h>

#define HD 4096   // H*D
#define Dd 128
#define Hh 32

// ---------- fp8 e4m3fn helpers (OCP on gfx950) ----------
__device__ inline float f8_quant_val(float x_over_scale) {
    // clamp to max finite so a 1-ulp overshoot of 448 can't become NaN
    float c = fminf(fmaxf(x_over_scale, -448.0f), 448.0f);
    __hip_fp8_e4m3 f8(c);
    return (float)f8;           // the quantized value itself (scale factored out)
}

__device__ inline unsigned char f8_quant_byte(float x_over_scale) {
    float c = fminf(fmaxf(x_over_scale, -448.0f), 448.0f);
    __hip_fp8_e4m3 f8(c);
    return (unsigned char)f8.__x;
}

__device__ inline float f8_decode(unsigned char b) {
    __hip_fp8_e4m3 f8;
    f8.__x = (__hip_fp8_storage_t)b;
    return (float)f8;
}

// ---------- kernel 1: per-tensor absmax ----------
__global__ void absmax_kernel(const float* __restrict__ x, int n4, unsigned* __restrict__ out) {
    int i = blockIdx.x * blockDim.x + threadIdx.x;
    int stride = gridDim.x * blockDim.x;
    const float4* x4 = (const float4*)x;
    float m = 0.0f;
    for (; i < n4; i += stride) {
        float4 v = x4[i];
        m = fmaxf(m, fmaxf(fmaxf(fabsf(v.x), fabsf(v.y)), fmaxf(fabsf(v.z), fabsf(v.w))));
    }
    #pragma unroll
    for (int s = 32; s >= 1; s >>= 1) m = fmaxf(m, __shfl_xor(m, s, 64));
    __shared__ float red[4];
    int wid = threadIdx.x >> 6;
    if ((threadIdx.x & 63) == 0) red[wid] = m;
    __syncthreads();
    if (threadIdx.x == 0) {
        float mm = fmaxf(fmaxf(red[0], red[1]), fmaxf(red[2], red[3]));
        atomicMax(out, __float_as_uint(mm));  // abs-bits compare correctly as uint
    }
}

// ---------- kernel 2: quantize tensor -> fp8 bytes (true fp32 division by scale) ----------
__global__ void quant_kernel(const float* __restrict__ x, unsigned char* __restrict__ q,
                             int n4, const unsigned* __restrict__ amax_bits) {
    float scale = __uint_as_float(*amax_bits) / 448.0f;
    int i = blockIdx.x * blockDim.x + threadIdx.x;
    int stride = gridDim.x * blockDim.x;
    const float4* x4 = (const float4*)x;
    unsigned* q4 = (unsigned*)q;
    for (; i < n4; i += stride) {
        float4 v = x4[i];
        unsigned p = (unsigned)f8_quant_byte(v.x / scale)
                   | ((unsigned)f8_quant_byte(v.y / scale) << 8)
                   | ((unsigned)f8_quant_byte(v.z / scale) << 16)
                   | ((unsigned)f8_quant_byte(v.w / scale) << 24);
        q4[i] = p;
    }
}

// ---------- kernel 3: causal varlen attention, 1 wave per query row ----------
__global__ __launch_bounds__(256)
void attn_kernel(const float* __restrict__ Q,
                 const unsigned char* __restrict__ K8,
                 const unsigned char* __restrict__ V8,
                 const int* __restrict__ q_off,
                 const int* __restrict__ k_off,
                 const int* __restrict__ k_lens,
                 int nB,
                 const unsigned* __restrict__ amax,
                 float* __restrict__ out, int total) {
    int h = blockIdx.y;
    int wid = threadIdx.x >> 6;
    int lane = threadIdx.x & 63;
    int t = blockIdx.x * 4 + wid;          // global query row
    if (t >= total) return;

    // find sequence b with q_off[b] <= t < q_off[b+1]
    int b = 0;
    while (q_off[b + 1] <= t) ++b;
    int q_start = q_off[b];
    int q_len   = q_off[b + 1] - q_start;
    int ks      = k_off[b];
    int klen    = k_lens[b];
    int q_local = t - q_start;
    int kmax = q_local + (klen - q_len) + 1;   // causal limit for varlen
    if (kmax > klen) kmax = klen;
    if (kmax <= 0) kmax = 0;

    float sq = __uint_as_float(amax[0]) / 448.0f;
    float sk = __uint_as_float(amax[1]) / 448.0f;
    float sv = __uint_as_float(amax[2]) / 448.0f;
    const float sm_scale = 0.08838834764831845f;
    float score_scale = sq * sk * sm_scale;    // scales factored out of the fp8 matmuls

    // load + quantize this wave's Q row: lane holds d = 2*lane, 2*lane+1
    const float* qrow = Q + (size_t)t * HD + h * Dd;
    float2 qv = ((const float2*)qrow)[lane];
    float q0 = f8_quant_val(qv.x / sq);
    float q1 = f8_quant_val(qv.y / sq);

    float m = -INFINITY, l = 0.0f, o0 = 0.0f, o1 = 0.0f;
    const unsigned char* Kbase = K8 + (size_t)ks * HD + h * Dd;
    const unsigned char* Vbase = V8 + (size_t)ks * HD + h * Dd;

    for (int k = 0; k < kmax; ++k) {
        uchar2 kb = ((const uchar2*)(Kbase + (size_t)k * HD))[lane];
        float k0 = f8_decode(kb.x), k1 = f8_decode(kb.y);
        float part = fmaf(q0, k0, q1 * k1);
        // 64-lane butterfly sum (all lanes get result)
        #pragma unroll
        for (int s = 32; s >= 1; s >>= 1) part += __shfl_xor(part, s, 64);
        float sc = part * score_scale;

        float mn = fmaxf(m, sc);
        float corr = __expf(m - mn);     // first iter: exp(-inf) = 0, safe
        float p = __expf(sc - mn);

        uchar2 vb = ((const uchar2*)(Vbase + (size_t)k * HD))[lane];
        float v0 = f8_decode(vb.x), v1 = f8_decode(vb.y);

        l  = fmaf(l, corr, p);
        o0 = fmaf(o0, corr, p * v0);
        o1 = fmaf(o1, corr, p * v1);
        m = mn;
    }

    float inv_l = sv / l;
    float2 ov = make_float2(o0 * inv_l, o1 * inv_l);
    ((float2*)(out + (size_t)t * HD + h * Dd))[lane] = ov;
}

extern "C" void kernel_launch(void* const* d_in, const int* in_sizes, int n_in,
                              void* d_out, int out_size, void* d_ws, size_t ws_size,
                              hipStream_t stream) {
    const float* q = (const float*)d_in[0];
    const float* k = (const float*)d_in[1];
    const float* v = (const float*)d_in[2];
    const int* q_off  = (const int*)d_in[3];
    const int* k_off  = (const int*)d_in[4];
    const int* k_lens = (const int*)d_in[5];

    int total = in_sizes[0] / HD;          // 4096
    int B = in_sizes[3] - 1;               // 4
    int n = in_sizes[0];                   // elements per tensor
    int n4 = n / 4;

    unsigned* amax = (unsigned*)d_ws;                          // [0]=q [1]=k [2]=v
    unsigned char* K8 = (unsigned char*)d_ws + 64;
    unsigned char* V8 = K8 + (size_t)n;

    hipMemsetAsync(d_ws, 0, 64, stream);

    absmax_kernel<<<1024, 256, 0, stream>>>(q, n4, amax + 0);
    absmax_kernel<<<1024, 256, 0, stream>>>(k, n4, amax + 1);
    absmax_kernel<<<1024, 256, 0, stream>>>(v, n4, amax + 2);

    quant_kernel<<<2048, 256, 0, stream>>>(k, K8, n4, amax + 1);
    quant_kernel<<<2048, 256, 0, stream>>>(v, V8, n4, amax + 2);

    dim3 grid((total + 3) / 4, Hh);
    attn_kernel<<<grid, 256, 0, stream>>>(q, K8, V8, q_off, k_off, k_lens, B,
                                          amax, (float*)d_out, total);
}

// Round 6
// 599.972 us; speedup vs baseline: 8.4382x; 8.4382x over previous
//
#include <hip/hip_runtime.h>
#include <hip/hip_fp8.h>

#define HD 4096   // H*D
#define Dd 128
#define Hh 32
#define QBLK 64
#define KVBLK 32
#define LDV 40    // padded LDS row length (bf16 elems): 80B rows keep 16B alignment

typedef float f32x4 __attribute__((ext_vector_type(4)));
typedef short s16x8 __attribute__((ext_vector_type(8)));

// fast hardware exp2 (v_exp_f32); avoids glibc __exp2f name collision
#define EXP2F(x) __builtin_amdgcn_exp2f(x)

// ---------- fp8 e4m3fn helpers (OCP on gfx950) ----------
__device__ inline unsigned char f8_quant_byte(float x_over_scale) {
    float c = fminf(fmaxf(x_over_scale, -448.0f), 448.0f);
    __hip_fp8_e4m3 f8(c);
    return (unsigned char)f8.__x;
}
__device__ inline float f8_decode(unsigned char b) {
    __hip_fp8_e4m3 f8;
    f8.__x = (__hip_fp8_storage_t)b;
    return (float)f8;
}
// fp32 -> bf16 bits, RNE (every e4m3 value is exact in bf16)
__device__ inline unsigned short bf16_bits(float f) {
    unsigned u = __float_as_uint(f);
    return (unsigned short)((u + 0x7FFFu + ((u >> 16) & 1u)) >> 16);
}
__device__ inline long pack8(const unsigned char* b) {
    unsigned lo = (unsigned)b[0] | ((unsigned)b[1] << 8) | ((unsigned)b[2] << 16) | ((unsigned)b[3] << 24);
    unsigned hi = (unsigned)b[4] | ((unsigned)b[5] << 8) | ((unsigned)b[6] << 16) | ((unsigned)b[7] << 24);
    return (long)(((unsigned long long)hi << 32) | lo);
}

// ---------- kernel 1: per-tensor absmax ----------
__global__ void absmax_kernel(const float* __restrict__ x, int n4, unsigned* __restrict__ out) {
    int i = blockIdx.x * blockDim.x + threadIdx.x;
    int stride = gridDim.x * blockDim.x;
    const float4* x4 = (const float4*)x;
    float m = 0.0f;
    for (; i < n4; i += stride) {
        float4 v = x4[i];
        m = fmaxf(m, fmaxf(fmaxf(fabsf(v.x), fabsf(v.y)), fmaxf(fabsf(v.z), fabsf(v.w))));
    }
    #pragma unroll
    for (int s = 32; s >= 1; s >>= 1) m = fmaxf(m, __shfl_xor(m, s, 64));
    __shared__ float red[4];
    int wid = threadIdx.x >> 6;
    if ((threadIdx.x & 63) == 0) red[wid] = m;
    __syncthreads();
    if (threadIdx.x == 0) {
        float mm = fmaxf(fmaxf(red[0], red[1]), fmaxf(red[2], red[3]));
        atomicMax(out, __float_as_uint(mm));
    }
}

// ---------- kernel 2: quantize tensor -> fp8 bytes (true fp32 division by scale) ----------
__global__ void quant_kernel(const float* __restrict__ x, unsigned char* __restrict__ q,
                             int n4, const unsigned* __restrict__ amax_bits) {
    float scale = __uint_as_float(*amax_bits) / 448.0f;
    int i = blockIdx.x * blockDim.x + threadIdx.x;
    int stride = gridDim.x * blockDim.x;
    const float4* x4 = (const float4*)x;
    unsigned* q4 = (unsigned*)q;
    for (; i < n4; i += stride) {
        float4 v = x4[i];
        unsigned p = (unsigned)f8_quant_byte(v.x / scale)
                   | ((unsigned)f8_quant_byte(v.y / scale) << 8)
                   | ((unsigned)f8_quant_byte(v.z / scale) << 16)
                   | ((unsigned)f8_quant_byte(v.w / scale) << 24);
        q4[i] = p;
    }
}

// ---------- kernel 3: MFMA flash attention ----------
// block: 64 q-rows x 1 head. 4 waves x 16 rows. kv tiles of 32.
// QK^T: mfma_f32_16x16x32_fp8_fp8 on raw quantized bytes (exact).
// PV:   mfma_f32_16x16x32_bf16 (P rounded to bf16; V exact in bf16).
__global__ __launch_bounds__(256)
void attn_mfma_kernel(const float* __restrict__ Q,
                      const unsigned char* __restrict__ K8,
                      const unsigned char* __restrict__ V8,
                      const int* __restrict__ q_off,
                      const int* __restrict__ k_off,
                      const int* __restrict__ k_lens,
                      const unsigned* __restrict__ amax,
                      float* __restrict__ out, int total, int nB) {
    __shared__ unsigned short VT[Dd][LDV];       // V^T tile (bf16): VT[d][kk]
    __shared__ unsigned short PL[4][16][LDV];    // per-wave P tile: PL[w][q][kk]

    const int h = blockIdx.y;
    const int tid = threadIdx.x;
    const int wid = tid >> 6, lane = tid & 63;
    const int g = lane >> 4, c = lane & 15;

    const int qb0 = blockIdx.x * QBLK;
    const int qw0 = qb0 + wid * 16;

    // sequence lookup (assumes a block does not span sequences: QBLK | seq length)
    int b = 0;
    while (b + 1 < nB && q_off[b + 1] <= qb0) ++b;
    const int q_start = q_off[b];
    const int q_len   = q_off[b + 1] - q_start;
    const int seq_ks  = k_off[b];
    const int klen    = k_lens[b];
    const int dkl     = klen - q_len;

    int tlast = qb0 + QBLK - 1; if (tlast >= total) tlast = total - 1;
    int kmax_blk = (tlast - q_start) + dkl + 1;
    if (kmax_blk > klen) kmax_blk = klen;
    if (kmax_blk < 0) kmax_blk = 0;
    const int ntiles = (kmax_blk + KVBLK - 1) / KVBLK;

    const float sq = __uint_as_float(amax[0]) / 448.0f;
    const float sk = __uint_as_float(amax[1]) / 448.0f;
    const float sv = __uint_as_float(amax[2]) / 448.0f;
    const float sm_scale = 0.08838834764831845f;
    const float sscale = sq * sk * sm_scale * 1.4426950408889634f;  // fold log2(e): use exp2

    // ---- Q fragments: quantize on the fly (A-frag: row=lane&15, k = 8*(lane>>4)+i) ----
    int qrow = qw0 + c; if (qrow >= total) qrow = total - 1;
    const float* qp = Q + (size_t)qrow * HD + h * Dd;
    long qfrag[4];
    #pragma unroll
    for (int s = 0; s < 4; ++s) {
        const float* qq = qp + s * 32 + g * 8;
        f32x4 va = *(const f32x4*)(qq);
        f32x4 vb = *(const f32x4*)(qq + 4);
        unsigned char by[8];
        #pragma unroll
        for (int i = 0; i < 4; ++i) by[i] = f8_quant_byte(va[i] / sq);
        #pragma unroll
        for (int i = 0; i < 4; ++i) by[4 + i] = f8_quant_byte(vb[i] / sq);
        qfrag[s] = pack8(by);
    }

    // causal limits per accumulator row (C-layout row = g*4 + r)
    int lim[4];
    #pragma unroll
    for (int r = 0; r < 4; ++r) lim[r] = (qw0 - q_start) + g * 4 + r + dkl;

    f32x4 Oacc[8];
    #pragma unroll
    for (int s = 0; s < 8; ++s) Oacc[s] = (f32x4){0.f, 0.f, 0.f, 0.f};
    float m_r[4] = {-1e30f, -1e30f, -1e30f, -1e30f};
    float l_r[4] = {0.f, 0.f, 0.f, 0.f};

    const unsigned char* Kb = K8 + (size_t)seq_ks * HD + h * Dd;
    const unsigned char* Vb = V8 + (size_t)seq_ks * HD + h * Dd;
    unsigned short* pl = &PL[wid][0][0];

    for (int kt = 0; kt < ntiles; ++kt) {
        __syncthreads();   // VT safe to overwrite (prev iter's PV reads done)

        // ---- stage V^T tile: coalesced 16B fp8 load, decode, transpose-write ----
        {
            int kk = tid >> 3, d0 = (tid & 7) * 16;
            int krow = kt * KVBLK + kk;
            bool ok = (krow < klen);
            uint4 raw = make_uint4(0u, 0u, 0u, 0u);
            if (ok) raw = *(const uint4*)(Vb + (size_t)krow * HD + d0);
            unsigned wv[4] = {raw.x, raw.y, raw.z, raw.w};
            #pragma unroll
            for (int j = 0; j < 16; ++j) {
                unsigned char byte = (unsigned char)((wv[j >> 2] >> ((j & 3) * 8)) & 0xFF);
                VT[d0 + j][kk] = ok ? bf16_bits(f8_decode(byte)) : (unsigned short)0;
            }
        }
        __syncthreads();

        // ---- QK^T: 2 kk-subtiles x 4 K-slices of fp8 MFMA ----
        int krow0 = kt * KVBLK + c;
        int krow1 = krow0 + 16;
        if (krow0 > klen - 1) krow0 = klen - 1;
        if (krow1 > klen - 1) krow1 = klen - 1;
        const unsigned char* kp0 = Kb + (size_t)krow0 * HD;
        const unsigned char* kp1 = Kb + (size_t)krow1 * HD;
        f32x4 S0 = {0.f, 0.f, 0.f, 0.f}, S1 = {0.f, 0.f, 0.f, 0.f};
        #pragma unroll
        for (int s = 0; s < 4; ++s) {
            long k0 = *(const long*)(kp0 + s * 32 + g * 8);
            long k1 = *(const long*)(kp1 + s * 32 + g * 8);
            S0 = __builtin_amdgcn_mfma_f32_16x16x32_fp8_fp8(qfrag[s], k0, S0, 0, 0, 0);
            S1 = __builtin_amdgcn_mfma_f32_16x16x32_fp8_fp8(qfrag[s], k1, S1, 0, 0, 0);
        }

        // ---- online softmax (rows live in 16-lane groups; reduce via shfl_xor 1,2,4,8) ----
        float cr[4];
        #pragma unroll
        for (int r = 0; r < 4; ++r) {
            float s0 = S0[r] * sscale, s1 = S1[r] * sscale;
            if (kt * KVBLK + c      > lim[r]) s0 = -3e38f;   // mask AFTER mfma kills any garbage
            if (kt * KVBLK + 16 + c > lim[r]) s1 = -3e38f;
            float t = fmaxf(s0, s1);
            t = fmaxf(t, __shfl_xor(t, 1, 64));
            t = fmaxf(t, __shfl_xor(t, 2, 64));
            t = fmaxf(t, __shfl_xor(t, 4, 64));
            t = fmaxf(t, __shfl_xor(t, 8, 64));
            float mn = fmaxf(m_r[r], t);
            cr[r] = EXP2F(m_r[r] - mn);
            m_r[r] = mn;
            float p0 = EXP2F(s0 - mn);
            float p1 = EXP2F(s1 - mn);
            float ps = p0 + p1;
            ps += __shfl_xor(ps, 1, 64);
            ps += __shfl_xor(ps, 2, 64);
            ps += __shfl_xor(ps, 4, 64);
            ps += __shfl_xor(ps, 8, 64);
            l_r[r] = l_r[r] * cr[r] + ps;
            pl[(g * 4 + r) * LDV + c]      = bf16_bits(p0);
            pl[(g * 4 + r) * LDV + 16 + c] = bf16_bits(p1);
        }
        // rescale O by corr
        #pragma unroll
        for (int sub = 0; sub < 8; ++sub) {
            #pragma unroll
            for (int r = 0; r < 4; ++r) Oacc[sub][r] *= cr[r];
        }

        __syncthreads();   // uniform barrier: P tiles visible (also orders VT reads below)

        // ---- PV: A = P (ds_read_b128), B = V^T columns (ds_read_b128) ----
        s16x8 pa = *(const s16x8*)(pl + c * LDV + g * 8);
        #pragma unroll
        for (int sub = 0; sub < 8; ++sub) {
            s16x8 vb = *(const s16x8*)(&VT[sub * 16 + c][g * 8]);
            Oacc[sub] = __builtin_amdgcn_mfma_f32_16x16x32_bf16(pa, vb, Oacc[sub], 0, 0, 0);
        }
    }

    // ---- epilogue ----
    #pragma unroll
    for (int r = 0; r < 4; ++r) {
        int t = qw0 + g * 4 + r;
        if (t < total) {
            float inv = (l_r[r] > 0.f) ? (sv / l_r[r]) : 0.f;
            float* op = out + (size_t)t * HD + h * Dd + c;
            #pragma unroll
            for (int sub = 0; sub < 8; ++sub) op[sub * 16] = Oacc[sub][r] * inv;
        }
    }
}

extern "C" void kernel_launch(void* const* d_in, const int* in_sizes, int n_in,
                              void* d_out, int out_size, void* d_ws, size_t ws_size,
                              hipStream_t stream) {
    const float* q = (const float*)d_in[0];
    const float* k = (const float*)d_in[1];
    const float* v = (const float*)d_in[2];
    const int* q_off  = (const int*)d_in[3];
    const int* k_off  = (const int*)d_in[4];
    const int* k_lens = (const int*)d_in[5];

    int total = in_sizes[0] / HD;          // 4096
    int B = in_sizes[3] - 1;               // 4
    int n = in_sizes[0];
    int n4 = n / 4;

    unsigned* amax = (unsigned*)d_ws;                          // [0]=q [1]=k [2]=v
    unsigned char* K8 = (unsigned char*)d_ws + 64;
    unsigned char* V8 = K8 + (size_t)n;

    (void)hipMemsetAsync(d_ws, 0, 64, stream);

    absmax_kernel<<<1024, 256, 0, stream>>>(q, n4, amax + 0);
    absmax_kernel<<<1024, 256, 0, stream>>>(k, n4, amax + 1);
    absmax_kernel<<<1024, 256, 0, stream>>>(v, n4, amax + 2);

    quant_kernel<<<2048, 256, 0, stream>>>(k, K8, n4, amax + 1);
    quant_kernel<<<2048, 256, 0, stream>>>(v, V8, n4, amax + 2);

    dim3 grid(total / QBLK, Hh);
    attn_mfma_kernel<<<grid, 256, 0, stream>>>(q, K8, V8, q_off, k_off, k_lens,
                                               amax, (float*)d_out, total, B);
}